// Round 4
// baseline (97.372 us; speedup 1.0000x reference)
//
#include <hip/hip_runtime.h>
#include <hip/hip_bf16.h>

// Problem constants
#define Bn   4
#define Cn   256
#define Dn   32
#define Hn   64
#define Wn   64
#define Kt   64          // top-k
#define PROJ 512
#define DHW  (Dn*Hn*Wn)  // 131072
#define HW   (Hn*Wn)     // 4096
#define VECLEN (Kt*Cn)   // 16384 per batch

#define NBIN 4096        // histogram on top 12 bits of sortable key
#define CAND 1024        // LDS candidate buffer (expected ~100-250 used)

// ---- workspace layout (bytes) ----
#define WS_IDX_OFF  0            // int   topk_idx[Bn*Kt]  = 1 KB
#define WS_VEC_OFF  (4*1024)     // float vec[Bn][VECLEN]  = 256 KB

// ---- d_out layout (float32 elements) ----
// [0, 768)     centers (B,K,3) as floats
// [768, 1024)  scores  (B,K)
// [1024, 3072) feature (B,PROJ)
#define OUT_SCORES 768
#define OUT_FEAT   1024

__device__ __forceinline__ unsigned f2sortable(float f) {
    unsigned u = __float_as_uint(f);
    return (u & 0x80000000u) ? ~u : (u | 0x80000000u);
}
__device__ __forceinline__ float sortable2f(unsigned u) {
    unsigned orig = (u & 0x80000000u) ? (u & 0x7FFFFFFFu) : ~u;
    return __uint_as_float(orig);
}

// ---------------- Fused top-k: one block per batch ------------------------
// hist (LDS) -> threshold scan (LDS) -> compact (re-stream, L2-hot) ->
// bitonic sort <=1024 candidates (LDS) -> emit centers/scores/idx.
__global__ __launch_bounds__(1024) void topk_kernel(
        const float* __restrict__ score, float* __restrict__ out,
        int* __restrict__ topk_idx) {
    __shared__ int lh[NBIN];                   // 16 KB
    __shared__ unsigned long long keys[CAND];  // 8 KB
    __shared__ int partial[256];
    __shared__ int s_cnt, s_thr;
    const int b   = blockIdx.x;
    const int tid = threadIdx.x;

    for (int i = tid; i < NBIN; i += 1024) lh[i] = 0;
    if (tid == 0) s_cnt = 0;
    __syncthreads();

    // pass 1: histogram of top-12 sortable bits
    const float4* src = (const float4*)(score + (size_t)b * DHW);
    for (int i = tid; i < DHW / 4; i += 1024) {
        float4 v = src[i];
        atomicAdd(&lh[f2sortable(v.x) >> 20], 1);
        atomicAdd(&lh[f2sortable(v.y) >> 20], 1);
        atomicAdd(&lh[f2sortable(v.z) >> 20], 1);
        atomicAdd(&lh[f2sortable(v.w) >> 20], 1);
    }
    __syncthreads();

    // threshold: suffix-sum from the top bin until cum >= Kt
    if (tid < 256) {
        int base = NBIN - 16 - 16 * tid;
        int s = 0;
        #pragma unroll
        for (int i = 0; i < 16; ++i) s += lh[base + i];
        partial[tid] = s;
    }
    __syncthreads();
    if (tid == 0) {
        int cum = 0, T = 0;
        for (int j = 0; j < 256; ++j) {
            if (cum + partial[j] >= Kt) {
                int bb = NBIN - 1 - 16 * j;
                for (int i = 0; i < 16; ++i) {
                    cum += lh[bb - i];
                    if (cum >= Kt) { T = bb - i; break; }
                }
                break;
            }
            cum += partial[j];
        }
        s_thr = T;
    }
    __syncthreads();
    const unsigned thr = (unsigned)s_thr;

    // pass 2: compact candidates >= threshold bin (score slice is L2-hot)
    for (int i = tid; i < DHW / 4; i += 1024) {
        float4 v = src[i];
        float vals[4] = {v.x, v.y, v.z, v.w};
        #pragma unroll
        for (int l = 0; l < 4; ++l) {
            unsigned u = f2sortable(vals[l]);
            if ((u >> 20) >= thr) {
                int pos = atomicAdd(&s_cnt, 1);
                if (pos < CAND)
                    keys[pos] = ((unsigned long long)u << 32) |
                                (0xFFFFFFFFu - (unsigned)(4 * i + l));
            }
        }
    }
    __syncthreads();

    int n = s_cnt;
    if (n > CAND) n = CAND;
    int P = 64;
    while (P < n) P <<= 1;   // P <= 1024
    for (int i = tid; i < P; i += 1024)
        if (i >= n) keys[i] = 0ULL;
    __syncthreads();

    // bitonic sort descending, one element per thread
    for (int k = 2; k <= P; k <<= 1) {
        for (int j = k >> 1; j > 0; j >>= 1) {
            if (tid < P) {
                int i = tid, ixj = i ^ j;
                if (ixj > i) {
                    unsigned long long a = keys[i], c = keys[ixj];
                    bool desc = ((i & k) == 0);
                    if (desc ? (a < c) : (a > c)) { keys[i] = c; keys[ixj] = a; }
                }
            }
            __syncthreads();
        }
    }

    if (tid < Kt) {
        unsigned long long kk = keys[tid];
        float sc = sortable2f((unsigned)(kk >> 32));
        unsigned gidx = 0xFFFFFFFFu - (unsigned)(kk & 0xFFFFFFFFu);
        int z = (int)(gidx >> 12);
        int y = (int)((gidx >> 6) & 63);
        int x = (int)(gidx & 63);
        int o = (b * Kt + tid) * 3;
        out[o + 0] = (float)z;
        out[o + 1] = (float)y;
        out[o + 2] = (float)x;
        out[OUT_SCORES + b * Kt + tid] = sc;
        topk_idx[b * Kt + tid] = (int)gidx;
    }
}

// ---------------- Gather: masked patch average per (b,k,c) ---------------
// 1024 threads: thread = (channel c, row-group r). Each 5-float row is
// covered by two aligned float4 loads ((x0&3)+5 <= 8); per-element masks
// are block-uniform 0/1 floats feeding FMAs. Second load skipped when the
// first block covers [x0, xe) -- also guarantees no OOB at the array end.
__global__ __launch_bounds__(1024) void gather_kernel(
        const float* __restrict__ fm, const int* __restrict__ topk_idx,
        float* __restrict__ vec) {
    __shared__ float red[4][Cn];
    const int bk  = blockIdx.x;        // Bn*Kt = 256
    const int b   = bk >> 6;
    const int tid = threadIdx.x;
    const int c   = tid & 255;
    const int r   = tid >> 8;          // 0..3

    const int idx = topk_idx[bk];
    const int z = idx >> 12;
    const int y = (idx >> 6) & 63;
    const int x = idx & 63;
    const int z0 = max(z - 2, 0), y0 = max(y - 2, 0), x0 = max(x - 2, 0);
    const int nz = min(5, Dn - z0), ny = min(5, Hn - y0), nx = min(5, Wn - x0);
    const int xe = x0 + nx;            // <= 64
    const int a0 = x0 & ~3;
    const bool need2 = (a0 + 4) < xe;  // if false, f4[0] covers the row

    float m[8];
    #pragma unroll
    for (int j = 0; j < 8; ++j) {
        int e = a0 + j;
        m[j] = (e >= x0 && e < xe) ? 1.f : 0.f;
    }

    const float* base = fm + ((size_t)(b * Cn + c)) * DHW
                           + (size_t)z0 * HW + (size_t)y0 * Wn;
    float s = 0.f;
    #pragma unroll
    for (int u = 0; u < 7; ++u) {
        int rr = r + 4 * u;
        if (rr < 25) {
            int iz = rr / 5, iy = rr % 5;
            if (iz < nz && iy < ny) {           // block-uniform branch
                const float* row = base + iz * HW + iy * Wn;
                float4 v0 = *(const float4*)(row + a0);
                s = fmaf(v0.x, m[0], s);
                s = fmaf(v0.y, m[1], s);
                s = fmaf(v0.z, m[2], s);
                s = fmaf(v0.w, m[3], s);
                if (need2) {                    // block-uniform branch
                    float4 v1 = *(const float4*)(row + a0 + 4);
                    s = fmaf(v1.x, m[4], s);
                    s = fmaf(v1.y, m[5], s);
                    s = fmaf(v1.z, m[6], s);
                    s = fmaf(v1.w, m[7], s);
                }
            }
        }
    }
    red[r][c] = s;
    __syncthreads();
    if (r == 0) {
        float t = (red[0][c] + red[1][c]) + (red[2][c] + red[3][c]);
        vec[((size_t)bk << 8) + c] = t / (float)(nz * ny * nx);
    }
}

// ---------------- GEMV: feature = vec @ Wp^T + b --------------------------
__global__ __launch_bounds__(256) void gemv_kernel(
        const float* __restrict__ vec, const float* __restrict__ Wp,
        const float* __restrict__ bias, float* __restrict__ out) {
    const int p   = blockIdx.x;        // PROJ
    const int tid = threadIdx.x;       // 256
    const float4* w4 = (const float4*)(Wp + (size_t)p * VECLEN);

    float acc[Bn] = {0.f, 0.f, 0.f, 0.f};
    for (int i = tid; i < VECLEN / 4; i += 256) {
        float4 wv = w4[i];
        #pragma unroll
        for (int bb = 0; bb < Bn; ++bb) {
            float4 vv = ((const float4*)(vec + bb * VECLEN))[i];
            acc[bb] += wv.x * vv.x + wv.y * vv.y + wv.z * vv.z + wv.w * vv.w;
        }
    }

    __shared__ float red[4][Bn];
    const int lane = tid & 63, wave = tid >> 6;
    #pragma unroll
    for (int bb = 0; bb < Bn; ++bb) {
        float v = acc[bb];
        #pragma unroll
        for (int off = 32; off > 0; off >>= 1) v += __shfl_down(v, off, 64);
        if (lane == 0) red[wave][bb] = v;
    }
    __syncthreads();
    if (tid < Bn) {
        int bb = tid;
        float t = red[0][bb] + red[1][bb] + red[2][bb] + red[3][bb];
        out[OUT_FEAT + bb * PROJ + p] = t + bias[p];
    }
}

extern "C" void kernel_launch(void* const* d_in, const int* in_sizes, int n_in,
                              void* d_out, int out_size, void* d_ws, size_t ws_size,
                              hipStream_t stream) {
    const float* fm    = (const float*)d_in[0];
    const float* score = (const float*)d_in[1];
    const float* Wp    = (const float*)d_in[2];
    const float* bias  = (const float*)d_in[3];
    float* out = (float*)d_out;

    char* ws = (char*)d_ws;
    int*   topk_idx = (int*)(ws + WS_IDX_OFF);
    float* vec      = (float*)(ws + WS_VEC_OFF);

    topk_kernel<<<Bn, 1024, 0, stream>>>(score, out, topk_idx);
    gather_kernel<<<Bn * Kt, 1024, 0, stream>>>(fm, topk_idx, vec);
    gemv_kernel<<<PROJ, 256, 0, stream>>>(vec, Wp, bias, out);
}

// Round 5
// 81.612 us; speedup vs baseline: 1.1931x; 1.1931x over previous
//
#include <hip/hip_runtime.h>
#include <hip/hip_bf16.h>

// Problem constants
#define Bn   4
#define Cn   256
#define Dn   32
#define Hn   64
#define Wn   64
#define Kt   64          // top-k
#define PROJ 512
#define DHW  (Dn*Hn*Wn)  // 131072
#define HW   (Hn*Wn)     // 4096
#define VECLEN (Kt*Cn)   // 16384 per batch

#define NBIN    4096     // histogram on top 12 bits of sortable key
#define CANDMAX 4096     // per-batch candidate buffer (expected ~100-300 used)

// ---- workspace layout (bytes) ----
#define WS_HIST_OFF 0            // int   hist[Bn][NBIN]        = 64 KB
#define WS_CNT_OFF  (64*1024)    // int   cand_cnt[Bn]          = 16 B
#define WS_IDX_OFF  (65*1024)    // int   topk_idx[Bn*Kt]       = 1 KB
#define WS_CAND_OFF (68*1024)    // u64   cand[Bn][CANDMAX]     = 128 KB
#define WS_VEC_OFF  (200*1024)   // float vec[Bn][VECLEN]       = 256 KB

// ---- d_out layout (float32 elements) ----
// [0, 768)     centers (B,K,3) as floats
// [768, 1024)  scores  (B,K)
// [1024, 3072) feature (B,PROJ)
#define OUT_SCORES 768
#define OUT_FEAT   1024

__device__ __forceinline__ unsigned f2sortable(float f) {
    unsigned u = __float_as_uint(f);
    return (u & 0x80000000u) ? ~u : (u | 0x80000000u);
}
__device__ __forceinline__ float sortable2f(unsigned u) {
    unsigned orig = (u & 0x80000000u) ? (u & 0x7FFFFFFFu) : ~u;
    return __uint_as_float(orig);
}

// ---------------- zero hist + counters (run every call) ------------------
__global__ __launch_bounds__(256) void zero_kernel(int* __restrict__ hist,
                                                   int* __restrict__ cnt) {
    int i = blockIdx.x * 256 + threadIdx.x;
    if (i < Bn * NBIN) hist[i] = 0;
    if (i < Bn) cnt[i] = 0;
}

// ---------------- Pass 1: 4096-bin histogram per batch -------------------
__global__ __launch_bounds__(256) void hist_kernel(
        const float* __restrict__ score, int* __restrict__ hist) {
    __shared__ int lh[NBIN];
    const int blk = blockIdx.x;
    const int b   = blk >> 3;
    const int sub = blk & 7;
    const int tid = threadIdx.x;

    for (int i = tid; i < NBIN; i += 256) lh[i] = 0;
    __syncthreads();

    const float4* src = (const float4*)(score + (size_t)b * DHW) + sub * 4096;
    for (int i = tid; i < 4096; i += 256) {
        float4 v = src[i];
        atomicAdd(&lh[f2sortable(v.x) >> 20], 1);
        atomicAdd(&lh[f2sortable(v.y) >> 20], 1);
        atomicAdd(&lh[f2sortable(v.z) >> 20], 1);
        atomicAdd(&lh[f2sortable(v.w) >> 20], 1);
    }
    __syncthreads();

    int* gh = hist + b * NBIN;
    for (int i = tid; i < NBIN; i += 256)
        if (lh[i]) atomicAdd(&gh[i], lh[i]);
}

// ---------------- Pass 2: find threshold bin, compact candidates ---------
__global__ __launch_bounds__(256) void compact_kernel(
        const float* __restrict__ score, const int* __restrict__ hist,
        unsigned long long* __restrict__ cand, int* __restrict__ cnt) {
    __shared__ int partial[256];
    __shared__ int thrBin;
    const int blk = blockIdx.x;
    const int b   = blk >> 3;
    const int sub = blk & 7;
    const int tid = threadIdx.x;
    const int* h  = hist + b * NBIN;

    // suffix scan from top bin: chunk t covers bins [4080-16t, 4095-16t]
    int base = NBIN - 16 - 16 * tid;
    int s = 0;
    #pragma unroll
    for (int i = 0; i < 16; ++i) s += h[base + i];
    partial[tid] = s;
    __syncthreads();
    if (tid == 0) {
        int cum = 0, T = 0;
        for (int j = 0; j < 256; ++j) {
            if (cum + partial[j] >= Kt) {
                int bb = NBIN - 1 - 16 * j;
                for (int i = 0; i < 16; ++i) {
                    cum += h[bb - i];
                    if (cum >= Kt) { T = bb - i; break; }
                }
                break;
            }
            cum += partial[j];
        }
        thrBin = T;
    }
    __syncthreads();
    const unsigned thr = (unsigned)thrBin;

    const float4* src = (const float4*)(score + (size_t)b * DHW) + sub * 4096;
    unsigned long long* cb = cand + (size_t)b * CANDMAX;
    for (int i = tid; i < 4096; i += 256) {
        float4 v = src[i];
        unsigned gbase = (unsigned)((sub * 4096 + i) * 4);
        float vals[4] = {v.x, v.y, v.z, v.w};
        #pragma unroll
        for (int l = 0; l < 4; ++l) {
            unsigned u = f2sortable(vals[l]);
            if ((u >> 20) >= thr) {
                int pos = atomicAdd(&cnt[b], 1);
                if (pos < CANDMAX)
                    cb[pos] = ((unsigned long long)u << 32) |
                              (0xFFFFFFFFu - (gbase + l));
            }
        }
    }
}

// ---------------- Pass 3: sort small candidate list, emit top-64 ---------
__global__ __launch_bounds__(512) void final_kernel(
        const unsigned long long* __restrict__ cand, const int* __restrict__ cnt,
        float* __restrict__ out, int* __restrict__ topk_idx) {
    __shared__ unsigned long long keys[CANDMAX];
    const int b   = blockIdx.x;
    const int tid = threadIdx.x;

    int n = cnt[b];
    if (n > CANDMAX) n = CANDMAX;
    int P = 64;
    while (P < n) P <<= 1;

    const unsigned long long* cb = cand + (size_t)b * CANDMAX;
    for (int i = tid; i < P; i += 512)
        keys[i] = (i < n) ? cb[i] : 0ULL;
    __syncthreads();

    for (int k = 2; k <= P; k <<= 1) {
        for (int j = k >> 1; j > 0; j >>= 1) {
            for (int i = tid; i < P; i += 512) {
                int ixj = i ^ j;
                if (ixj > i) {
                    unsigned long long a = keys[i], c = keys[ixj];
                    bool desc = ((i & k) == 0);
                    if (desc ? (a < c) : (a > c)) { keys[i] = c; keys[ixj] = a; }
                }
            }
            __syncthreads();
        }
    }

    if (tid < Kt) {
        unsigned long long kk = keys[tid];
        float score = sortable2f((unsigned)(kk >> 32));
        unsigned gidx = 0xFFFFFFFFu - (unsigned)(kk & 0xFFFFFFFFu);
        int z = (int)(gidx >> 12);
        int y = (int)((gidx >> 6) & 63);
        int x = (int)(gidx & 63);
        int o = (b * Kt + tid) * 3;
        out[o + 0] = (float)z;
        out[o + 1] = (float)y;
        out[o + 2] = (float)x;
        out[OUT_SCORES + b * Kt + tid] = score;
        topk_idx[b * Kt + tid] = (int)gidx;
    }
}

// ---------------- Gather: masked patch average per (b,k,c) ---------------
// LANE = k swizzle: a wave's 64 simultaneous addresses are 64 scattered
// patch locations within one channel slice (diverse channel/bank bits),
// instead of 64 channels at exact 512 KB stride. Each thread computes the
// full 125-tap clamped sum for its (b,k,c); rows via <=2 aligned float4
// with 0/1 masks feeding FMAs. grid = Bn*64 blocks (c-groups of 4) x 256.
__global__ __launch_bounds__(256) void gather_kernel(
        const float* __restrict__ fm, const int* __restrict__ topk_idx,
        float* __restrict__ vec) {
    const int blk = blockIdx.x;        // Bn*64 = 256
    const int b   = blk >> 6;
    const int cg  = blk & 63;
    const int tid = threadIdx.x;
    const int k   = tid & 63;          // lane = k
    const int c   = cg * 4 + (tid >> 6);

    const int idx = topk_idx[b * Kt + k];
    const int z = idx >> 12;
    const int y = (idx >> 6) & 63;
    const int x = idx & 63;
    const int z0 = max(z - 2, 0), y0 = max(y - 2, 0), x0 = max(x - 2, 0);
    const int nz = min(5, Dn - z0), ny = min(5, Hn - y0), nx = min(5, Wn - x0);
    const int xe = x0 + nx;            // <= 64
    const int a0 = x0 & ~3;
    const bool need2 = (a0 + 4) < xe;  // second float4 needed (per-lane)

    float m[8];
    #pragma unroll
    for (int j = 0; j < 8; ++j) {
        int e = a0 + j;
        m[j] = (e >= x0 && e < xe) ? 1.f : 0.f;
    }

    const float* base = fm + ((size_t)(b * Cn + c)) * DHW
                           + (size_t)z0 * HW + (size_t)y0 * Wn;
    float s = 0.f;
    #pragma unroll
    for (int iz = 0; iz < 5; ++iz) {
        #pragma unroll
        for (int iy = 0; iy < 5; ++iy) {
            if (iz < nz && iy < ny) {          // per-lane predication
                const float* row = base + iz * HW + iy * Wn;
                float4 v0 = *(const float4*)(row + a0);
                s = fmaf(v0.x, m[0], s);
                s = fmaf(v0.y, m[1], s);
                s = fmaf(v0.z, m[2], s);
                s = fmaf(v0.w, m[3], s);
                if (need2) {
                    float4 v1 = *(const float4*)(row + a0 + 4);
                    s = fmaf(v1.x, m[4], s);
                    s = fmaf(v1.y, m[5], s);
                    s = fmaf(v1.z, m[6], s);
                    s = fmaf(v1.w, m[7], s);
                }
            }
        }
    }
    vec[((size_t)(b * Kt + k) << 8) + c] = s / (float)(nz * ny * nx);
}

// ---------------- GEMV: feature = vec @ Wp^T + b --------------------------
__global__ __launch_bounds__(256) void gemv_kernel(
        const float* __restrict__ vec, const float* __restrict__ Wp,
        const float* __restrict__ bias, float* __restrict__ out) {
    const int p   = blockIdx.x;        // PROJ
    const int tid = threadIdx.x;       // 256
    const float4* w4 = (const float4*)(Wp + (size_t)p * VECLEN);

    float acc[Bn] = {0.f, 0.f, 0.f, 0.f};
    for (int i = tid; i < VECLEN / 4; i += 256) {
        float4 wv = w4[i];
        #pragma unroll
        for (int bb = 0; bb < Bn; ++bb) {
            float4 vv = ((const float4*)(vec + bb * VECLEN))[i];
            acc[bb] += wv.x * vv.x + wv.y * vv.y + wv.z * vv.z + wv.w * vv.w;
        }
    }

    __shared__ float red[4][Bn];
    const int lane = tid & 63, wave = tid >> 6;
    #pragma unroll
    for (int bb = 0; bb < Bn; ++bb) {
        float v = acc[bb];
        #pragma unroll
        for (int off = 32; off > 0; off >>= 1) v += __shfl_down(v, off, 64);
        if (lane == 0) red[wave][bb] = v;
    }
    __syncthreads();
    if (tid < Bn) {
        int bb = tid;
        float t = red[0][bb] + red[1][bb] + red[2][bb] + red[3][bb];
        out[OUT_FEAT + bb * PROJ + p] = t + bias[p];
    }
}

extern "C" void kernel_launch(void* const* d_in, const int* in_sizes, int n_in,
                              void* d_out, int out_size, void* d_ws, size_t ws_size,
                              hipStream_t stream) {
    const float* fm    = (const float*)d_in[0];
    const float* score = (const float*)d_in[1];
    const float* Wp    = (const float*)d_in[2];
    const float* bias  = (const float*)d_in[3];
    float* out = (float*)d_out;

    char* ws = (char*)d_ws;
    int*   hist     = (int*)(ws + WS_HIST_OFF);
    int*   cand_cnt = (int*)(ws + WS_CNT_OFF);
    int*   topk_idx = (int*)(ws + WS_IDX_OFF);
    unsigned long long* cand = (unsigned long long*)(ws + WS_CAND_OFF);
    float* vec      = (float*)(ws + WS_VEC_OFF);

    zero_kernel<<<(Bn * NBIN + 255) / 256, 256, 0, stream>>>(hist, cand_cnt);
    hist_kernel<<<Bn * 8, 256, 0, stream>>>(score, hist);
    compact_kernel<<<Bn * 8, 256, 0, stream>>>(score, hist, cand, cand_cnt);
    final_kernel<<<Bn, 512, 0, stream>>>(cand, cand_cnt, out, topk_idx);
    gather_kernel<<<Bn * 64, 256, 0, stream>>>(fm, topk_idx, vec);
    gemv_kernel<<<PROJ, 256, 0, stream>>>(vec, Wp, bias, out);
}